// Round 1
// baseline (289.913 us; speedup 1.0000x reference)
//
#include <hip/hip_runtime.h>

#define D 128
#define NSEG 2048
#define EPSV 1e-6f
#define BLOCK 512
#define CPR 32           // float4 chunks per row (128/4)
#define RG (BLOCK/CPR)   // 16 row-groups

__global__ __launch_bounds__(BLOCK) void graphnorm_fused(
    const float* __restrict__ feat,
    const int* __restrict__ seg,
    const float* __restrict__ weight,
    const float* __restrict__ bias,
    const float* __restrict__ mean_scale,
    float* __restrict__ out,
    int N)
{
    const int s = blockIdx.x;
    __shared__ int s_range[2];
    __shared__ float4 s_sum[RG][CPR];   // 8 KB
    __shared__ float4 s_sq[RG][CPR];    // 8 KB
    __shared__ float4 s_a[CPR];
    __shared__ float4 s_b[CPR];

    const int t = threadIdx.x;

    // lower_bound for segment s (thread 0) and s+1 (thread 1)
    if (t < 2) {
        int target = s + t;
        int lo = 0, hi = N;
        while (lo < hi) {
            int mid = (lo + hi) >> 1;
            if (seg[mid] < target) lo = mid + 1; else hi = mid;
        }
        s_range[t] = lo;
    }
    __syncthreads();
    const int start = s_range[0];
    const int end   = s_range[1];

    const int c = t & (CPR - 1);   // float4 column chunk 0..31
    const int g = t >> 5;          // row group 0..15

    const float4* feat4 = reinterpret_cast<const float4*>(feat);
    float4* out4 = reinterpret_cast<float4*>(out);

    // ---- pass 1: per-column sum and sum-of-squares ----
    float4 sum = make_float4(0.f, 0.f, 0.f, 0.f);
    float4 sq  = make_float4(0.f, 0.f, 0.f, 0.f);
    for (int r = start + g; r < end; r += RG) {
        float4 v = feat4[r * CPR + c];
        sum.x += v.x; sum.y += v.y; sum.z += v.z; sum.w += v.w;
        sq.x += v.x * v.x; sq.y += v.y * v.y;
        sq.z += v.z * v.z; sq.w += v.w * v.w;
    }
    s_sum[g][c] = sum;
    s_sq[g][c]  = sq;
    __syncthreads();

    // tree reduce over row groups
    for (int st = RG / 2; st > 0; st >>= 1) {
        if (g < st) {
            float4 a = s_sum[g][c], b = s_sum[g + st][c];
            a.x += b.x; a.y += b.y; a.z += b.z; a.w += b.w;
            s_sum[g][c] = a;
            float4 p = s_sq[g][c], q = s_sq[g + st][c];
            p.x += q.x; p.y += q.y; p.z += q.z; p.w += q.w;
            s_sq[g][c] = p;
        }
        __syncthreads();
    }

    // ---- per-column affine coefficients ----
    if (g == 0) {
        const float cnt = (float)max(end - start, 1);
        const float inv = 1.0f / cnt;
        const float4 sm = s_sum[0][c];
        const float4 sg = s_sq[0][c];
        const float4 w   = reinterpret_cast<const float4*>(weight)[c];
        const float4 bi  = reinterpret_cast<const float4*>(bias)[c];
        const float4 msc = reinterpret_cast<const float4*>(mean_scale)[c];
        float4 A, B;
        #define COEF(comp)                                                  \
        {                                                                   \
            float mean = sm.comp * inv;                                     \
            float ms   = mean * msc.comp;                                   \
            float var  = fmaxf(sg.comp * inv - 2.f * mean * ms + ms * ms, 0.f); \
            float istd = rsqrtf(var + EPSV);                                \
            A.comp = w.comp * istd;                                         \
            B.comp = bi.comp - A.comp * ms;                                 \
        }
        COEF(x) COEF(y) COEF(z) COEF(w)
        #undef COEF
        s_a[c] = A;
        s_b[c] = B;
    }
    __syncthreads();

    // ---- pass 2: apply out = a*x + b ----
    const float4 A = s_a[c];
    const float4 B = s_b[c];
    for (int r = start + g; r < end; r += RG) {
        const int idx = r * CPR + c;
        float4 v = feat4[idx];
        float4 o;
        o.x = fmaf(A.x, v.x, B.x);
        o.y = fmaf(A.y, v.y, B.y);
        o.z = fmaf(A.z, v.z, B.z);
        o.w = fmaf(A.w, v.w, B.w);
        out4[idx] = o;
    }
}

extern "C" void kernel_launch(void* const* d_in, const int* in_sizes, int n_in,
                              void* d_out, int out_size, void* d_ws, size_t ws_size,
                              hipStream_t stream) {
    const float* feat       = (const float*)d_in[0];
    const int*   seg        = (const int*)d_in[1];
    const float* weight     = (const float*)d_in[2];
    const float* bias       = (const float*)d_in[3];
    const float* mean_scale = (const float*)d_in[4];
    float* out = (float*)d_out;

    const int N = in_sizes[0] / D;   // 1,000,000

    graphnorm_fused<<<NSEG, BLOCK, 0, stream>>>(
        feat, seg, weight, bias, mean_scale, out, N);
}

// Round 3
// 238.162 us; speedup vs baseline: 1.2173x; 1.2173x over previous
//
#include <hip/hip_runtime.h>

#define D 128
#define NSEG 2048
#define EPSV 1e-6f
#define BLOCK 512
#define CPR 32           // float4 chunks per row (128/4)
#define RG (BLOCK/CPR)   // 16 row-groups
#define WAVES (BLOCK/64) // 8

typedef float f32x4 __attribute__((ext_vector_type(4)));

#define ACC(v, sum, sq) { (sum) += (v); (sq) += (v) * (v); }

__global__ __launch_bounds__(BLOCK) void graphnorm_fused(
    const float* __restrict__ feat,
    const int* __restrict__ seg,
    const float* __restrict__ weight,
    const float* __restrict__ bias,
    const float* __restrict__ mean_scale,
    float* __restrict__ out,
    int N)
{
    const int s = blockIdx.x;
    __shared__ int s_range[2];
    __shared__ f32x4 s_sum[WAVES][CPR];  // 4 KB
    __shared__ f32x4 s_sq[WAVES][CPR];   // 4 KB
    __shared__ f32x4 s_a[CPR];
    __shared__ f32x4 s_b[CPR];

    const int t = threadIdx.x;

    // lower_bound for segment s (thread 0) and s+1 (thread 1)
    if (t < 2) {
        int target = s + t;
        int lo = 0, hi = N;
        while (lo < hi) {
            int mid = (lo + hi) >> 1;
            if (seg[mid] < target) lo = mid + 1; else hi = mid;
        }
        s_range[t] = lo;
    }
    __syncthreads();
    const int start = s_range[0];
    const int end   = s_range[1];

    const int c = t & (CPR - 1);   // float4 column chunk 0..31
    const int g = t >> 5;          // row group 0..15

    const f32x4* feat4 = reinterpret_cast<const f32x4*>(feat);
    f32x4* out4 = reinterpret_cast<f32x4*>(out);

    // ---- pass 1: per-column sum and sum-of-squares, 4-deep unroll ----
    f32x4 s0 = 0.f, s1 = 0.f, s2 = 0.f, s3 = 0.f;
    f32x4 q0 = 0.f, q1 = 0.f, q2 = 0.f, q3 = 0.f;

    int r = start + g;
    for (; r + 3 * RG < end; r += 4 * RG) {
        f32x4 v0 = feat4[(r         ) * CPR + c];
        f32x4 v1 = feat4[(r +     RG) * CPR + c];
        f32x4 v2 = feat4[(r + 2 * RG) * CPR + c];
        f32x4 v3 = feat4[(r + 3 * RG) * CPR + c];
        ACC(v0, s0, q0);
        ACC(v1, s1, q1);
        ACC(v2, s2, q2);
        ACC(v3, s3, q3);
    }
    for (; r < end; r += RG) {
        f32x4 v = feat4[r * CPR + c];
        ACC(v, s0, q0);
    }
    s0 += s1; s2 += s3; s0 += s2;
    q0 += q1; q2 += q3; q0 += q2;

    // wave-level reduce: lanes l and l^32 hold the same column chunk c
    #pragma unroll
    for (int i = 0; i < 4; ++i) {
        s0[i] += __shfl_xor(s0[i], 32);
        q0[i] += __shfl_xor(q0[i], 32);
    }

    const int w    = t >> 6;   // wave id 0..7
    const int lane = t & 63;
    if (lane < 32) {
        s_sum[w][c] = s0;
        s_sq[w][c]  = q0;
    }
    __syncthreads();

    // ---- per-column affine coefficients (threads 0..31) ----
    if (t < CPR) {
        f32x4 sm = s_sum[0][t];
        f32x4 sg = s_sq[0][t];
        #pragma unroll
        for (int i = 1; i < WAVES; ++i) {
            sm += s_sum[i][t];
            sg += s_sq[i][t];
        }
        const float cnt = (float)max(end - start, 1);
        const float inv = 1.0f / cnt;
        const f32x4 wv  = reinterpret_cast<const f32x4*>(weight)[t];
        const f32x4 bi  = reinterpret_cast<const f32x4*>(bias)[t];
        const f32x4 msc = reinterpret_cast<const f32x4*>(mean_scale)[t];
        f32x4 A, B;
        #pragma unroll
        for (int i = 0; i < 4; ++i) {
            float mean = sm[i] * inv;
            float ms   = mean * msc[i];
            float var  = fmaxf(sg[i] * inv - 2.f * mean * ms + ms * ms, 0.f);
            float istd = rsqrtf(var + EPSV);
            A[i] = wv[i] * istd;
            B[i] = bi[i] - A[i] * ms;
        }
        s_a[t] = A;
        s_b[t] = B;
    }
    __syncthreads();

    // ---- pass 2: apply out = a*x + b, 4-deep unroll, nontemporal stores ----
    const f32x4 A = s_a[c];
    const f32x4 B = s_b[c];

    r = start + g;
    for (; r + 3 * RG < end; r += 4 * RG) {
        const int i0 = (r         ) * CPR + c;
        const int i1 = (r +     RG) * CPR + c;
        const int i2 = (r + 2 * RG) * CPR + c;
        const int i3 = (r + 3 * RG) * CPR + c;
        f32x4 v0 = feat4[i0];
        f32x4 v1 = feat4[i1];
        f32x4 v2 = feat4[i2];
        f32x4 v3 = feat4[i3];
        __builtin_nontemporal_store(A * v0 + B, &out4[i0]);
        __builtin_nontemporal_store(A * v1 + B, &out4[i1]);
        __builtin_nontemporal_store(A * v2 + B, &out4[i2]);
        __builtin_nontemporal_store(A * v3 + B, &out4[i3]);
    }
    for (; r < end; r += RG) {
        const int idx = r * CPR + c;
        f32x4 v = feat4[idx];
        __builtin_nontemporal_store(A * v + B, &out4[idx]);
    }
}

extern "C" void kernel_launch(void* const* d_in, const int* in_sizes, int n_in,
                              void* d_out, int out_size, void* d_ws, size_t ws_size,
                              hipStream_t stream) {
    const float* feat       = (const float*)d_in[0];
    const int*   seg        = (const int*)d_in[1];
    const float* weight     = (const float*)d_in[2];
    const float* bias       = (const float*)d_in[3];
    const float* mean_scale = (const float*)d_in[4];
    float* out = (float*)d_out;

    const int N = in_sizes[0] / D;   // 1,000,000

    graphnorm_fused<<<NSEG, BLOCK, 0, stream>>>(
        feat, seg, weight, bias, mean_scale, out, N);
}